// Round 9
// baseline (318.320 us; speedup 1.0000x reference)
//
#include <hip/hip_runtime.h>
#include <hip/hip_bf16.h>

// KAN layer = GEMM: out[b,o] = sum_{i,k} T_k(tanh(x[b,i])) * W[o,i,k] + bias[o]
// v6: REGISTER-ONLY main loop. No LDS staging, no barriers, no inline asm,
// no hand-counted vmcnt -> no race surface at all (spills can only slow it).
//   - A-fragments: cheb8(x) computed per lane into registers (A never exists).
//   - B-fragments: global_load_dwordx4 straight to registers. Each fragment
//     = 16 cols x 32 k x bf16 = 16 fully-used 64B cache lines.
//   - Block = 64x64 output tile, 128 threads = 2 waves SPLIT-K (wave w owns
//     k in [w*4096,(w+1)*4096)); one LDS merge + bias at the end.
//   - Grid 1024 blocks -> 4 blocks/CU, 2 waves/SIMD (2x the TLP of v1-v5).
//   - XCD swizzle: XCD x serves n-blocks {2x,2x+1} only -> its 2MB B-stripe
//     stays L2-resident (without this, 1GB of B re-reads would hit L3).
#define MD 4096
#define ND 1024
#define KD 8192
#define IN_F 1024

typedef __bf16 bf16x8 __attribute__((ext_vector_type(8)));
typedef float f32x4 __attribute__((ext_vector_type(4)));

// ---------------- Pass 1: W fp32 -> bf16 (48 MB traffic, ~10 us) ----------
#define N_CONV ((ND * KD) / 8)

__global__ __launch_bounds__(256) void conv_kernel(
    const float* __restrict__ w, __bf16* __restrict__ B) {
  int j = blockIdx.x * blockDim.x + threadIdx.x;  // grid is exact, no tail
  const float4* p = (const float4*)(w + (size_t)j * 8);
  float4 a = p[0], b = p[1];
  bf16x8 v;
  v[0] = (__bf16)a.x; v[1] = (__bf16)a.y; v[2] = (__bf16)a.z; v[3] = (__bf16)a.w;
  v[4] = (__bf16)b.x; v[5] = (__bf16)b.y; v[6] = (__bf16)b.z; v[7] = (__bf16)b.w;
  *(bf16x8*)(B + (size_t)j * 8) = v;
}

// ---------------- Pass 2: fused basis + GEMM_BT + bias ----------------
__device__ __forceinline__ bf16x8 cheb8(float xs) {
  // fast tanh: copysign(1 - 2/(exp2(2*log2(e)*|x|) + 1), x); |err| ~1e-7.
  float ax = __builtin_fabsf(xs);
  float e = __builtin_amdgcn_exp2f(ax * 2.88539008177792681472f);
  float r = __builtin_amdgcn_rcpf(e + 1.0f);
  float t = 1.0f - 2.0f * r;
  t = __builtin_copysignf(t, xs);
  float two_t = 2.0f * t;
  float T0 = 1.0f;
  float T1 = t;
  float T2 = two_t * T1 - T0;
  float T3 = two_t * T2 - T1;
  float T4 = two_t * T3 - T2;
  float T5 = two_t * T4 - T3;
  float T6 = two_t * T5 - T4;
  float T7 = two_t * T6 - T5;
  bf16x8 v;
  v[0] = (__bf16)T0; v[1] = (__bf16)T1; v[2] = (__bf16)T2; v[3] = (__bf16)T3;
  v[4] = (__bf16)T4; v[5] = (__bf16)T5; v[6] = (__bf16)T6; v[7] = (__bf16)T7;
  return v;
}

__global__ __launch_bounds__(128, 2) void gemm_bias(
    const float* __restrict__ x, const __bf16* __restrict__ B,
    const float* __restrict__ bias, float* __restrict__ C) {
  // merge buffer only (epilogue). Col-major-ish [col][row], stride 72 floats
  // keeps f32x4 slots 16B-aligned (c*288 B) and conflicts to ~4-way, once.
  __shared__ float Cred[64][72];  // 18.4 KB -> still 4 blocks/CU

  const int tid = threadIdx.x;
  const int w = tid >> 6;       // 0..1 : K-half owner
  const int lane = tid & 63;
  const int fr = lane & 15;     // frag row/col-within-16
  const int qk = lane >> 4;     // 0..3 : k-subchunk

  // XCD swizzle (1024 blocks % 8 == 0 -> bijective): XCD x -> n-blocks
  // {2x, 2x+1}, marching m-major so consecutive blocks share x row-panels.
  const int bid = blockIdx.x;
  const int xcd = bid & 7;
  const int idx = bid >> 3;            // 0..127
  const int n0 = (xcd * 2 + (idx & 1)) * 64;
  const int m0 = (idx >> 1) * 64;

  // ---- per-lane operand pointers (all #pragma unroll -> static indexing)
  const __bf16* bp[4];  // B row (= out col) pointers, at this wave's K-half
#pragma unroll
  for (int ni = 0; ni < 4; ni++)
    bp[ni] = B + (size_t)(n0 + ni * 16 + fr) * KD + w * 4096 + qk * 8;
  const float* xp[4];   // x row pointers, feature base = w*512 + qk
#pragma unroll
  for (int mi = 0; mi < 4; mi++)
    xp[mi] = x + (size_t)(m0 + mi * 16 + fr) * IN_F + w * 512 + qk;

  f32x4 acc[4][4];
#pragma unroll
  for (int i = 0; i < 4; i++)
#pragma unroll
    for (int j = 0; j < 4; j++) acc[i][j] = (f32x4){0.f, 0.f, 0.f, 0.f};

  // ---- prefetch t=0 (k-step = 64 elems: chunks c=0,1 of 32; frag k=qk*8+j)
  bf16x8 bcur[4][2];
  float xcur[4][2];
#pragma unroll
  for (int ni = 0; ni < 4; ni++) {
    bcur[ni][0] = *(const bf16x8*)(bp[ni]);
    bcur[ni][1] = *(const bf16x8*)(bp[ni] + 32);
  }
#pragma unroll
  for (int mi = 0; mi < 4; mi++) {
    xcur[mi][0] = xp[mi][0];
    xcur[mi][1] = xp[mi][4];
  }

  // ---- main loop: 64 K-steps of 64 per wave. Pure dataflow: prefetch t+1
  // (plain register loads; compiler inserts exact waitcnts), cheb + 32 MFMA
  // on t. No barriers, nothing shared.
#pragma unroll 2
  for (int t = 0; t < 64; ++t) {
    const int tn = (t + 1) & 63;  // last prefetch wraps to valid t=0 (unused)
    bf16x8 bnxt[4][2];
    float xnxt[4][2];
#pragma unroll
    for (int ni = 0; ni < 4; ni++) {
      bnxt[ni][0] = *(const bf16x8*)(bp[ni] + tn * 64);
      bnxt[ni][1] = *(const bf16x8*)(bp[ni] + tn * 64 + 32);
    }
#pragma unroll
    for (int mi = 0; mi < 4; mi++) {
      xnxt[mi][0] = xp[mi][tn * 8];
      xnxt[mi][1] = xp[mi][tn * 8 + 4];
    }
#pragma unroll
    for (int mi = 0; mi < 4; mi++) {
      bf16x8 a0 = cheb8(xcur[mi][0]);  // A-frag rows mi*16+fr, feat 8t+qk
      bf16x8 a1 = cheb8(xcur[mi][1]);  // feat 8t+4+qk
#pragma unroll
      for (int ni = 0; ni < 4; ni++) {
        acc[mi][ni] = __builtin_amdgcn_mfma_f32_16x16x32_bf16(
            a0, bcur[ni][0], acc[mi][ni], 0, 0, 0);
        acc[mi][ni] = __builtin_amdgcn_mfma_f32_16x16x32_bf16(
            a1, bcur[ni][1], acc[mi][ni], 0, 0, 0);
      }
    }
#pragma unroll
    for (int ni = 0; ni < 4; ni++) {
      bcur[ni][0] = bnxt[ni][0];
      bcur[ni][1] = bnxt[ni][1];
    }
#pragma unroll
    for (int mi = 0; mi < 4; mi++) {
      xcur[mi][0] = xnxt[mi][0];
      xcur[mi][1] = xnxt[mi][1];
    }
  }

  // ---- split-K merge + bias. C/D layout (proven): col=lane&15, row=qk*4+r.
  if (w == 1) {
#pragma unroll
    for (int mi = 0; mi < 4; mi++)
#pragma unroll
      for (int ni = 0; ni < 4; ni++)
        *(f32x4*)&Cred[ni * 16 + fr][mi * 16 + qk * 4] = acc[mi][ni];
  }
  __syncthreads();
  if (w == 0) {
#pragma unroll
    for (int ni = 0; ni < 4; ni++) {
      const int col = n0 + ni * 16 + fr;
      const float bv = bias[col];
#pragma unroll
      for (int mi = 0; mi < 4; mi++) {
        f32x4 other = *(const f32x4*)&Cred[ni * 16 + fr][mi * 16 + qk * 4];
#pragma unroll
        for (int r = 0; r < 4; r++)
          C[(size_t)(m0 + mi * 16 + qk * 4 + r) * ND + col] =
              acc[mi][ni][r] + other[r] + bv;
      }
    }
  }
}

extern "C" void kernel_launch(void* const* d_in, const int* in_sizes, int n_in,
                              void* d_out, int out_size, void* d_ws, size_t ws_size,
                              hipStream_t stream) {
  const float* x = (const float*)d_in[0];     // [4096,1024]
  const float* w = (const float*)d_in[1];     // [1024,1024,8]
  const float* bias = (const float*)d_in[2];  // [1024]
  float* out = (float*)d_out;                 // [4096,1024]

  __bf16* Bbf = (__bf16*)d_ws;  // 1024*8192 bf16 = 16 MB

  conv_kernel<<<N_CONV / 256, 256, 0, stream>>>(w, Bbf);

  // 1024 blocks (64x64 tiles), 128 threads (2 waves, split-K) each.
  gemm_bias<<<1024, 128, 0, stream>>>(x, Bbf, bias, out);
}

// Round 10
// 187.848 us; speedup vs baseline: 1.6946x; 1.6946x over previous
//
#include <hip/hip_runtime.h>
#include <hip/hip_bf16.h>

// KAN layer = GEMM: out[b,o] = sum_{i,k} T_k(tanh(x[b,i])) * W[o,i,k] + bias[o]
// v8 = R0 (the session-best two-pass kernel, gemm 110us + prep 20us) with ONE
// change: A-resident XCD grid swizzle in the GEMM.
//   R0's FETCH was 272 MB vs ~80 compulsory: XCD was implicitly n-stripe-
//   resident, so every A-tile was pulled by all 8 XCDs (~190 MB HBM leak).
//   New mapping b = xcd + 8*(n + 8*mloc): XCD k owns m-tiles [8k,8k+8),
//   sweeping all 8 n-tiles per m-tile -> A-tile (1 MB) L2-resident, read
//   once per byte; B (16 MB) re-reads come from L3.
#define MD 4096
#define ND 1024
#define KD 8192
#define IN_F 1024

typedef __bf16 bf16x8 __attribute__((ext_vector_type(8)));
typedef float f32x4 __attribute__((ext_vector_type(4)));

// ---------------- Pass 1 (merged): basis + W convert ----------------
// First N_BASIS threads: one x element -> 8 Chebyshev bf16.
// Next  N_CONV  threads: 8 fp32 W -> 8 bf16.
#define N_BASIS (MD * IN_F)
#define N_CONV ((ND * KD) / 8)

__global__ __launch_bounds__(256) void prep_kernel(
    const float* __restrict__ x, const float* __restrict__ w,
    __bf16* __restrict__ A, __bf16* __restrict__ B) {
  int i = blockIdx.x * blockDim.x + threadIdx.x;
  if (i < N_BASIS) {
    float t = tanhf(x[i]);
    float two_t = 2.0f * t;
    float T0 = 1.0f;
    float T1 = t;
    float T2 = two_t * T1 - T0;
    float T3 = two_t * T2 - T1;
    float T4 = two_t * T3 - T2;
    float T5 = two_t * T4 - T3;
    float T6 = two_t * T5 - T4;
    float T7 = two_t * T6 - T5;
    bf16x8 v;
    v[0] = (__bf16)T0; v[1] = (__bf16)T1; v[2] = (__bf16)T2; v[3] = (__bf16)T3;
    v[4] = (__bf16)T4; v[5] = (__bf16)T5; v[6] = (__bf16)T6; v[7] = (__bf16)T7;
    *(bf16x8*)(A + (size_t)i * 8) = v;
  } else if (i < N_BASIS + N_CONV) {
    int j = i - N_BASIS;
    const float4* p = (const float4*)(w + (size_t)j * 8);
    float4 a = p[0], b = p[1];
    bf16x8 v;
    v[0] = (__bf16)a.x; v[1] = (__bf16)a.y; v[2] = (__bf16)a.z; v[3] = (__bf16)a.w;
    v[4] = (__bf16)b.x; v[5] = (__bf16)b.y; v[6] = (__bf16)b.z; v[7] = (__bf16)b.w;
    *(bf16x8*)(B + (size_t)j * 8) = v;
  }
}

// ---------------- Pass 2: GEMM_BT + bias ----------------
// BM=64, BN=128, BK=64; 256 threads = 4 waves (2x2), wave tile 32x64 (2x4 of 16x16).
// LDS XOR swizzle: logical 16B group g of row r lives at physical group g^(r&7).
// Swizzle applied on the GLOBAL address side during staging (global_load_lds
// forces LDS dst = base + lane*16), and on the index side during fragment reads.
#define BM 64
#define BN 128
#define BK 64

__global__ __launch_bounds__(256) void gemm_bias(
    const __bf16* __restrict__ A, const __bf16* __restrict__ B,
    const float* __restrict__ bias, float* __restrict__ C) {
  __shared__ __align__(16) __bf16 As[BM * BK];
  __shared__ __align__(16) __bf16 Bs[BN * BK];

  const int tid = threadIdx.x;
  const int wave = tid >> 6;
  const int lane = tid & 63;

  // ---- A-resident XCD swizzle. Dispatch is round-robin: XCD = b % 8.
  // b = xcd + 8*(nt + 8*mloc); XCD k owns m-tiles {8k..8k+7}, n fastest:
  // the 1 MB A-tile stays L2-resident across its 8 n-blocks; B re-reads
  // (16 MB per mloc sweep) are L3 hits.
  const int b = blockIdx.x;
  const int xcd = b & 7;
  const int j = b >> 3;        // 0..63
  const int nt = j & 7;        // 0..7
  const int mloc = j >> 3;     // 0..7
  const int n0 = nt * BN;
  const int m0 = (xcd * 8 + mloc) * BM;

  const int wm = wave >> 1;   // 0..1
  const int wn = wave & 1;    // 0..1

  // ---- staging: one global_load_lds (16B/lane) covers 8 rows of 128B.
  // lane -> row ar = lane>>3 (r&7 == ar), physical group pg = lane&7.
  // Physical slot (r,pg) must hold logical group pg^ar -> load that column.
  const int ar = lane >> 3;                  // 0..7
  const int swz_col = ((lane & 7) ^ ar) * 8; // swizzled 8-elem column group
  const __bf16* gA = A + (size_t)(m0 + wave * 16 + ar) * KD + swz_col;
  const __bf16* gB = B + (size_t)(n0 + wave * 32 + ar) * KD + swz_col;
  const __bf16* lA = As + (wave * 16) * BK;
  const __bf16* lB = Bs + (wave * 32) * BK;

  f32x4 acc[2][4];
#pragma unroll
  for (int i = 0; i < 2; i++)
#pragma unroll
    for (int jj = 0; jj < 4; jj++) acc[i][jj] = (f32x4){0.f, 0.f, 0.f, 0.f};

  // ---- fragment coords (16x16x32: m=lane&15, k=(lane>>4)*8+j)
  const int fr = lane & 15;
  const int fr7 = fr & 7;
  const int qk = lane >> 4;  // 0..3

  for (int kt = 0; kt < KD; kt += BK) {
#pragma unroll
    for (int jj = 0; jj < 2; jj++)
      __builtin_amdgcn_global_load_lds(
          (const __attribute__((address_space(1))) void*)(gA + kt + (size_t)jj * 8 * KD),
          (__attribute__((address_space(3))) void*)(lA + jj * 8 * BK), 16, 0, 0);
#pragma unroll
    for (int jj = 0; jj < 4; jj++)
      __builtin_amdgcn_global_load_lds(
          (const __attribute__((address_space(1))) void*)(gB + kt + (size_t)jj * 8 * KD),
          (__attribute__((address_space(3))) void*)(lB + jj * 8 * BK), 16, 0, 0);
    __syncthreads();

#pragma unroll
    for (int s = 0; s < 2; s++) {
      // logical 16B group gl = s*4 + qk; physical = gl ^ (row&7) = gl ^ fr7
      const int pa = ((s * 4 + qk) ^ fr7) * 8;
      bf16x8 af[2], bfr[4];
#pragma unroll
      for (int mi = 0; mi < 2; mi++)
        af[mi] = *(const bf16x8*)&As[(wm * 32 + mi * 16 + fr) * BK + pa];
#pragma unroll
      for (int ni = 0; ni < 4; ni++)
        bfr[ni] = *(const bf16x8*)&Bs[(wn * 64 + ni * 16 + fr) * BK + pa];
#pragma unroll
      for (int mi = 0; mi < 2; mi++)
#pragma unroll
        for (int ni = 0; ni < 4; ni++)
          acc[mi][ni] = __builtin_amdgcn_mfma_f32_16x16x32_bf16(
              af[mi], bfr[ni], acc[mi][ni], 0, 0, 0);
    }
    __syncthreads();
  }

  // ---- epilogue: C/D layout col=lane&15, row=(lane>>4)*4+r ; add bias
  const int col0 = n0 + wn * 64;
  const int row0 = m0 + wm * 32 + (lane >> 4) * 4;
#pragma unroll
  for (int ni = 0; ni < 4; ni++) {
    int col = col0 + ni * 16 + (lane & 15);
    float bv = bias[col];
#pragma unroll
    for (int mi = 0; mi < 2; mi++) {
      int row = row0 + mi * 16;
#pragma unroll
      for (int r = 0; r < 4; r++)
        C[(size_t)(row + r) * ND + col] = acc[mi][ni][r] + bv;
    }
  }
}

extern "C" void kernel_launch(void* const* d_in, const int* in_sizes, int n_in,
                              void* d_out, int out_size, void* d_ws, size_t ws_size,
                              hipStream_t stream) {
  const float* x = (const float*)d_in[0];     // [4096,1024]
  const float* w = (const float*)d_in[1];     // [1024,1024,8]
  const float* bias = (const float*)d_in[2];  // [1024]
  float* out = (float*)d_out;                 // [4096,1024]

  __bf16* Abf = (__bf16*)d_ws;  // 4096*8192 bf16 = 64 MB
  __bf16* Bbf = (__bf16*)((char*)d_ws + (size_t)MD * KD * 2);  // 16 MB

  {  // merged basis + convert
    int n = N_BASIS + N_CONV;
    prep_kernel<<<(n + 255) / 256, 256, 0, stream>>>(x, w, Abf, Bbf);
  }
  {  // GEMM + bias: 512 blocks, 1D grid for the XCD-aware mapping
    gemm_bias<<<512, 256, 0, stream>>>(Abf, Bbf, bias, out);
  }
}

// Round 12
// 183.668 us; speedup vs baseline: 1.7331x; 1.0228x over previous
//
#include <hip/hip_runtime.h>
#include <hip/hip_bf16.h>

// KAN layer = GEMM: out[b,o] = sum_{i,k} T_k(tanh(x[b,i])) * W[o,i,k] + bias[o]
// v9 = v8's two-pass scheme with a 128x128 GEMM tile (4 waves, wave-tile 64x64).
//   Why: v8's counters show the LDS unit ~68% busy (48 KB ds_read per K-step
//   for 64 MFMA = 768 B/MFMA). 128x128/4-wave cuts that to 512 B/MFMA.
//   Grid drops to 256 blocks = 1 block/CU -> no cross-block TLP, so the
//   barrier drain is removed structurally: triple-buffered LDS, ONE s_barrier
//   per K-step, counted vmcnt(8) (the v4-proven pattern; here the loop's VMEM
//   stream is EXACTLY the 8 global_load_lds per iter - no other VMEM).
//   A-resident XCD swizzle kept: XCD k owns m-tiles [4k,4k+4), n fastest.
#define MD 4096
#define ND 1024
#define KD 8192
#define IN_F 1024

typedef __bf16 bf16x8 __attribute__((ext_vector_type(8)));
typedef float f32x4 __attribute__((ext_vector_type(4)));

// ---------------- Pass 1 (merged): basis + W convert ----------------
#define N_BASIS (MD * IN_F)
#define N_CONV ((ND * KD) / 8)

__global__ __launch_bounds__(256) void prep_kernel(
    const float* __restrict__ x, const float* __restrict__ w,
    __bf16* __restrict__ A, __bf16* __restrict__ B) {
  int i = blockIdx.x * blockDim.x + threadIdx.x;
  if (i < N_BASIS) {
    float t = tanhf(x[i]);
    float two_t = 2.0f * t;
    float T0 = 1.0f;
    float T1 = t;
    float T2 = two_t * T1 - T0;
    float T3 = two_t * T2 - T1;
    float T4 = two_t * T3 - T2;
    float T5 = two_t * T4 - T3;
    float T6 = two_t * T5 - T4;
    float T7 = two_t * T6 - T5;
    bf16x8 v;
    v[0] = (__bf16)T0; v[1] = (__bf16)T1; v[2] = (__bf16)T2; v[3] = (__bf16)T3;
    v[4] = (__bf16)T4; v[5] = (__bf16)T5; v[6] = (__bf16)T6; v[7] = (__bf16)T7;
    *(bf16x8*)(A + (size_t)i * 8) = v;
  } else if (i < N_BASIS + N_CONV) {
    int j = i - N_BASIS;
    const float4* p = (const float4*)(w + (size_t)j * 8);
    float4 a = p[0], b = p[1];
    bf16x8 v;
    v[0] = (__bf16)a.x; v[1] = (__bf16)a.y; v[2] = (__bf16)a.z; v[3] = (__bf16)a.w;
    v[4] = (__bf16)b.x; v[5] = (__bf16)b.y; v[6] = (__bf16)b.z; v[7] = (__bf16)b.w;
    *(bf16x8*)(B + (size_t)j * 8) = v;
  }
}

// ---------------- Pass 2: GEMM_BT + bias ----------------
#define BM 128
#define BN 128
#define BK 64
#define NT (KD / BK)       // 128 K-steps
#define TSZ (BM * BK)      // 8192 bf16 = 16 KB per tile buffer

__global__ __launch_bounds__(256, 1) void gemm_bias(
    const __bf16* __restrict__ A, const __bf16* __restrict__ B,
    const float* __restrict__ bias, float* __restrict__ C) {
  __shared__ __align__(16) __bf16 As[3][TSZ];  // 48 KB
  __shared__ __align__(16) __bf16 Bs[3][TSZ];  // 48 KB

  const int tid = threadIdx.x;
  const int wave = tid >> 6;   // 0..3
  const int lane = tid & 63;

  // A-resident XCD swizzle (dispatch round-robin: XCD = b % 8, validated R10):
  // b = xcd + 8*(nt + 8*mloc); XCD k owns m-tiles {4k..4k+3}, n fastest ->
  // 2 MB A-tile L2-resident; B re-reads (16 MB per m-sweep) are L3 hits.
  const int b = blockIdx.x;
  const int xcd = b & 7;
  const int j = b >> 3;        // 0..31
  const int nt = j & 7;        // 0..7
  const int mloc = j >> 3;     // 0..3
  const int n0 = nt * BN;
  const int m0 = (xcd * 4 + mloc) * BM;

  const int wm = wave >> 1;    // 0..1
  const int wn = wave & 1;     // 0..1

  // ---- staging: one global_load_lds (16B/lane) covers 8 rows of 128B.
  // lane -> row ar = lane>>3 (row&7 == ar), physical group pg = lane&7.
  // XOR swizzle on the GLOBAL side: slot (r,pg) holds logical group pg^ar.
  // Wave stages A rows [wave*32, wave*32+32) and B rows likewise (4+4 loads).
  const int ar = lane >> 3;
  const int swz_col = ((lane & 7) ^ ar) * 8;
  const __bf16* gA = A + (size_t)(m0 + wave * 32 + ar) * KD + swz_col;
  const __bf16* gB = B + (size_t)(n0 + wave * 32 + ar) * KD + swz_col;
  const int loff = wave * 32 * BK;  // element offset of this wave's slice

  f32x4 acc[4][4];
#pragma unroll
  for (int i = 0; i < 4; i++)
#pragma unroll
    for (int jj = 0; jj < 4; jj++) acc[i][jj] = (f32x4){0.f, 0.f, 0.f, 0.f};

  // ---- fragment coords (16x16x32: row=lane&15, k=(lane>>4)*8+jj)
  const int fr = lane & 15;
  const int fr7 = fr & 7;
  const int qk = lane >> 4;   // 0..3

  // ---- prologue: stage(0) -> buf0 (exactly 8 VMEM ops/wave)
#pragma unroll
  for (int jj = 0; jj < 4; jj++) {
    __builtin_amdgcn_global_load_lds(
        (const __attribute__((address_space(1))) void*)(gA + (size_t)jj * 8 * KD),
        (__attribute__((address_space(3))) void*)(&As[0][loff + jj * 8 * BK]), 16, 0, 0);
    __builtin_amdgcn_global_load_lds(
        (const __attribute__((address_space(1))) void*)(gB + (size_t)jj * 8 * KD),
        (__attribute__((address_space(3))) void*)(&Bs[0][loff + jj * 8 * BK]), 16, 0, 0);
  }

  // Per iter T: pre-barrier stage(T+1)->buf[NXT] (8 ops); WAIT; s_barrier;
  // post-barrier ds_read buf[CUR] + 32 MFMA.
  // vmcnt(8): 8 newest (this iter's stage) may stay in flight; everything
  // older (stage(T)) is complete. Loop VMEM stream is ONLY these 8 ops ->
  // the count is exact (VGPR ~130, no spill scratch traffic).
  // Skew safety (1 barrier, 3 buffers): between barrier T and T+1, reads hit
  // buf[T%3], in-flight DMA targets buf[(T+1)%3] and buf[(T+2)%3] - disjoint.
#define ITER(T, CUR, NXT, WAIT)                                                \
  do {                                                                         \
    const int tn = ((T) + 1 < NT) ? (T) + 1 : 0;                               \
    _Pragma("unroll") for (int jj = 0; jj < 4; jj++) {                         \
      __builtin_amdgcn_global_load_lds(                                        \
          (const __attribute__((address_space(1))) void*)(                     \
              gA + (size_t)tn * BK + (size_t)jj * 8 * KD),                     \
          (__attribute__((address_space(3))) void*)(                           \
              &As[NXT][loff + jj * 8 * BK]), 16, 0, 0);                        \
      __builtin_amdgcn_global_load_lds(                                        \
          (const __attribute__((address_space(1))) void*)(                     \
              gB + (size_t)tn * BK + (size_t)jj * 8 * KD),                     \
          (__attribute__((address_space(3))) void*)(                           \
              &Bs[NXT][loff + jj * 8 * BK]), 16, 0, 0);                        \
    }                                                                          \
    asm volatile(WAIT ::: "memory");                                           \
    __builtin_amdgcn_s_barrier();                                              \
    asm volatile("" ::: "memory");                                             \
    _Pragma("unroll") for (int s = 0; s < 2; s++) {                            \
      const int pa = ((s * 4 + qk) ^ fr7) * 8;                                 \
      bf16x8 af[4], bfr[4];                                                    \
      _Pragma("unroll") for (int mi = 0; mi < 4; mi++)                         \
          af[mi] = *(const bf16x8*)&As[CUR][(wm * 64 + mi * 16 + fr) * BK + pa]; \
      _Pragma("unroll") for (int ni = 0; ni < 4; ni++)                         \
          bfr[ni] = *(const bf16x8*)&Bs[CUR][(wn * 64 + ni * 16 + fr) * BK + pa]; \
      _Pragma("unroll") for (int mi = 0; mi < 4; mi++)                         \
          _Pragma("unroll") for (int ni = 0; ni < 4; ni++)                     \
              acc[mi][ni] = __builtin_amdgcn_mfma_f32_16x16x32_bf16(           \
                  af[mi], bfr[ni], acc[mi][ni], 0, 0, 0);                      \
    }                                                                          \
  } while (0)

  ITER(0, 0, 1, "s_waitcnt vmcnt(0)");   // belt-and-braces full drain once
  ITER(1, 1, 2, "s_waitcnt vmcnt(8)");
  ITER(2, 2, 0, "s_waitcnt vmcnt(8)");
#pragma unroll 1
  for (int t0 = 3; t0 < 126; t0 += 3) {  // iters 3..125, buffer phase static
    ITER(t0, 0, 1, "s_waitcnt vmcnt(8)");
    ITER(t0 + 1, 1, 2, "s_waitcnt vmcnt(8)");
    ITER(t0 + 2, 2, 0, "s_waitcnt vmcnt(8)");
  }
  ITER(126, 0, 1, "s_waitcnt vmcnt(8)");
  ITER(127, 1, 2, "s_waitcnt vmcnt(8)");
#undef ITER

  // ---- epilogue: C/D layout col=lane&15, row=(lane>>4)*4+r ; add bias
  const int col0 = n0 + wn * 64;
  const int row0 = m0 + wm * 64 + qk * 4;
#pragma unroll
  for (int ni = 0; ni < 4; ni++) {
    int col = col0 + ni * 16 + fr;
    float bv = bias[col];
#pragma unroll
    for (int mi = 0; mi < 4; mi++) {
      int row = row0 + mi * 16;
#pragma unroll
      for (int r = 0; r < 4; r++)
        C[(size_t)(row + r) * ND + col] = acc[mi][ni][r] + bv;
    }
  }
}

extern "C" void kernel_launch(void* const* d_in, const int* in_sizes, int n_in,
                              void* d_out, int out_size, void* d_ws, size_t ws_size,
                              hipStream_t stream) {
  const float* x = (const float*)d_in[0];     // [4096,1024]
  const float* w = (const float*)d_in[1];     // [1024,1024,8]
  const float* bias = (const float*)d_in[2];  // [1024]
  float* out = (float*)d_out;                 // [4096,1024]

  __bf16* Abf = (__bf16*)d_ws;  // 4096*8192 bf16 = 64 MB
  __bf16* Bbf = (__bf16*)((char*)d_ws + (size_t)MD * KD * 2);  // 16 MB

  {  // merged basis + convert
    int n = N_BASIS + N_CONV;
    prep_kernel<<<(n + 255) / 256, 256, 0, stream>>>(x, w, Abf, Bbf);
  }
  {  // GEMM + bias: 256 blocks (128x128 tiles), 1 block/CU
    gemm_bias<<<256, 256, 0, stream>>>(Abf, Bbf, bias, out);
  }
}